// Round 1
// baseline (1192.585 us; speedup 1.0000x reference)
//
#include <hip/hip_runtime.h>

#define NSEQ 2048
#define BATCH 4

// Y[b][m][n] = sum_k W[m][k] * X[b][k][n] (+ bias[m])
// grid: (NSEQ/64, M/64, BATCH), block 256. W row-major (M,K); X (B,K,NSEQ); Y (B,M,NSEQ).
template<bool BIAS>
__global__ __launch_bounds__(256)
void gemm_wx(const float* __restrict__ W, const float* __restrict__ X,
             const float* __restrict__ bias, float* __restrict__ Y, int K)
{
    const int n0 = blockIdx.x * 64;
    const int m0 = blockIdx.y * 64;
    const int M  = gridDim.y * 64;
    const int b  = blockIdx.z;
    const int tid = threadIdx.x;
    const int tx = tid & 15, ty = tid >> 4;

    const float* Xb = X + (size_t)b * K * NSEQ;
    float* Yb = Y + (size_t)b * M * NSEQ;

    __shared__ float As[64][17];   // +1 pad breaks bank aliasing on column reads
    __shared__ float Bs[16][64];

    float acc[4][4] = {};

    const int arow = tid >> 2, acol = (tid & 3) << 2;
    const int brow = tid >> 4, bcol = (tid & 15) << 2;

    for (int k0 = 0; k0 < K; k0 += 16) {
        float4 a4 = *(const float4*)(W + (size_t)(m0 + arow) * K + k0 + acol);
        float4 b4 = *(const float4*)(Xb + (size_t)(k0 + brow) * NSEQ + n0 + bcol);
        As[arow][acol + 0] = a4.x; As[arow][acol + 1] = a4.y;
        As[arow][acol + 2] = a4.z; As[arow][acol + 3] = a4.w;
        *(float4*)&Bs[brow][bcol] = b4;
        __syncthreads();
        #pragma unroll
        for (int kk = 0; kk < 16; ++kk) {
            float a[4];
            #pragma unroll
            for (int i = 0; i < 4; ++i) a[i] = As[ty * 4 + i][kk];
            float4 bb = *(const float4*)&Bs[kk][tx * 4];
            #pragma unroll
            for (int i = 0; i < 4; ++i) {
                acc[i][0] += a[i] * bb.x; acc[i][1] += a[i] * bb.y;
                acc[i][2] += a[i] * bb.z; acc[i][3] += a[i] * bb.w;
            }
        }
        __syncthreads();
    }
    #pragma unroll
    for (int i = 0; i < 4; ++i) {
        float bi = BIAS ? bias[m0 + ty * 4 + i] : 0.f;
        float4 r;
        r.x = acc[i][0] + bi; r.y = acc[i][1] + bi;
        r.z = acc[i][2] + bi; r.w = acc[i][3] + bi;
        *(float4*)(Yb + (size_t)(m0 + ty * 4 + i) * NSEQ + n0 + tx * 4) = r;
    }
}

// Flash attention, fp32. qkv layout: [b][3*512][n]; q=rows h*64..h*64+63, k at +512 rows, v at +1024.
// grid: (NSEQ/128, HEADS, BATCH), block 256.
// Each thread: one query, one 32-wide d-half. Lane l pairs with l^32 (same query, other half).
__global__ __launch_bounds__(256)
void attn_kernel(const float* __restrict__ qkv, float* __restrict__ out)
{
    const int ib = blockIdx.x;
    const int h  = blockIdx.y;
    const int b  = blockIdx.z;
    const int tid  = threadIdx.x;
    const int lane = tid & 63;
    const int wv   = tid >> 6;                       // 0..3
    const int qi   = ib * 128 + wv * 32 + (lane & 31);
    const int dh   = lane >> 5;                      // 0 or 1
    const int dbase = dh * 32;

    const float* qp = qkv + (size_t)b * 1536 * NSEQ + (size_t)(h * 64) * NSEQ;
    const float* kp = qp + (size_t)512 * NSEQ;
    const float* vp = kp + (size_t)512 * NSEQ;

    __shared__ float Ks[32][68];   // [j][d], row = 272 B (16B-aligned), reads are broadcast
    __shared__ float Vs[32][68];

    float qreg[32];
    #pragma unroll
    for (int dd = 0; dd < 32; ++dd)
        qreg[dd] = qp[(size_t)(dbase + dd) * NSEQ + qi] * 0.125f;   // SCALE = 64^-0.5

    float o[32];
    #pragma unroll
    for (int dd = 0; dd < 32; ++dd) o[dd] = 0.f;
    float m = -1e30f, l = 0.f;

    for (int j0 = 0; j0 < NSEQ; j0 += 32) {
        __syncthreads();
        #pragma unroll
        for (int s = 0; s < 2; ++s) {
            int f  = tid + s * 256;       // 0..511
            int d  = f >> 3;              // 0..63
            int jj = (f & 7) << 2;        // 0,4,..,28
            float4 k4 = *(const float4*)(kp + (size_t)d * NSEQ + j0 + jj);
            Ks[jj + 0][d] = k4.x; Ks[jj + 1][d] = k4.y;
            Ks[jj + 2][d] = k4.z; Ks[jj + 3][d] = k4.w;
            float4 v4 = *(const float4*)(vp + (size_t)d * NSEQ + j0 + jj);
            Vs[jj + 0][d] = v4.x; Vs[jj + 1][d] = v4.y;
            Vs[jj + 2][d] = v4.z; Vs[jj + 3][d] = v4.w;
        }
        __syncthreads();

        float s[32];
        #pragma unroll
        for (int jj = 0; jj < 32; ++jj) {
            float acc = 0.f;
            #pragma unroll
            for (int d4 = 0; d4 < 8; ++d4) {
                float4 k4 = *(const float4*)&Ks[jj][dbase + d4 * 4];
                acc += qreg[d4 * 4 + 0] * k4.x + qreg[d4 * 4 + 1] * k4.y
                     + qreg[d4 * 4 + 2] * k4.z + qreg[d4 * 4 + 3] * k4.w;
            }
            s[jj] = acc;
        }
        // combine the two d-halves: lane^32 holds same query's other half
        #pragma unroll
        for (int jj = 0; jj < 32; ++jj) s[jj] += __shfl_xor(s[jj], 32, 64);

        float tmax = s[0];
        #pragma unroll
        for (int jj = 1; jj < 32; ++jj) tmax = fmaxf(tmax, s[jj]);
        float mnew  = fmaxf(m, tmax);
        float alpha = __expf(m - mnew);
        float psum  = 0.f;
        #pragma unroll
        for (int jj = 0; jj < 32; ++jj) { s[jj] = __expf(s[jj] - mnew); psum += s[jj]; }
        l = l * alpha + psum;
        m = mnew;
        #pragma unroll
        for (int dd = 0; dd < 32; ++dd) o[dd] *= alpha;
        #pragma unroll
        for (int jj = 0; jj < 32; ++jj) {
            float p = s[jj];
            #pragma unroll
            for (int d4 = 0; d4 < 8; ++d4) {
                float4 v4 = *(const float4*)&Vs[jj][dbase + d4 * 4];
                o[d4 * 4 + 0] += p * v4.x; o[d4 * 4 + 1] += p * v4.y;
                o[d4 * 4 + 2] += p * v4.z; o[d4 * 4 + 3] += p * v4.w;
            }
        }
    }

    const float inv = 1.f / l;
    // out layout: [b][(h*64+d)][n]  ('b h n d -> b (h d) n')
    float* op = out + (size_t)b * 512 * NSEQ + (size_t)(h * 64) * NSEQ;
    #pragma unroll
    for (int dd = 0; dd < 32; ++dd)
        op[(size_t)(dbase + dd) * NSEQ + qi] = o[dd] * inv;
}

extern "C" void kernel_launch(void* const* d_in, const int* in_sizes, int n_in,
                              void* d_out, int out_size, void* d_ws, size_t ws_size,
                              hipStream_t stream)
{
    const float* x     = (const float*)d_in[0];   // (4,256,2048)
    const float* w_qkv = (const float*)d_in[1];   // (1536,256)
    const float* w_out = (const float*)d_in[2];   // (256,512)
    const float* b_out = (const float*)d_in[3];   // (256,)
    float* out  = (float*)d_out;                  // (4,256,2048)

    float* qkv  = (float*)d_ws;                              // 4*1536*2048 f32 = 50 MB
    float* attn = qkv + (size_t)BATCH * 1536 * NSEQ;         // 4*512*2048 f32 = 16 MB

    // qkv = w_qkv @ x  (per batch)
    gemm_wx<false><<<dim3(NSEQ / 64, 1536 / 64, BATCH), 256, 0, stream>>>(
        w_qkv, x, nullptr, qkv, 256);
    // flash attention -> attn (b, 512, n)
    attn_kernel<<<dim3(NSEQ / 128, 8, BATCH), 256, 0, stream>>>(qkv, attn);
    // out = w_out @ attn + b_out
    gemm_wx<true><<<dim3(NSEQ / 64, 256 / 64, BATCH), 256, 0, stream>>>(
        w_out, attn, b_out, out, 512);
}

// Round 2
// 357.055 us; speedup vs baseline: 3.3401x; 3.3401x over previous
//
#include <hip/hip_runtime.h>
#include <hip/hip_bf16.h>

#define NSEQ 2048
#define BATCH 4
#define LDF 72   // bf16 LDS row stride (64 + 8 pad, keeps 16B alignment, 2-way max conflict)

typedef __attribute__((ext_vector_type(8))) short bf16x8;
typedef __attribute__((ext_vector_type(4))) float f32x4;

// ---------------- fp32 tiled GEMM (unchanged from R1) ----------------
template<bool BIAS>
__global__ __launch_bounds__(256)
void gemm_wx(const float* __restrict__ W, const float* __restrict__ X,
             const float* __restrict__ bias, float* __restrict__ Y, int K)
{
    const int n0 = blockIdx.x * 64;
    const int m0 = blockIdx.y * 64;
    const int M  = gridDim.y * 64;
    const int b  = blockIdx.z;
    const int tid = threadIdx.x;
    const int tx = tid & 15, ty = tid >> 4;

    const float* Xb = X + (size_t)b * K * NSEQ;
    float* Yb = Y + (size_t)b * M * NSEQ;

    __shared__ float As[64][17];
    __shared__ float Bs[16][64];

    float acc[4][4] = {};
    const int arow = tid >> 2, acol = (tid & 3) << 2;
    const int brow = tid >> 4, bcol = (tid & 15) << 2;

    for (int k0 = 0; k0 < K; k0 += 16) {
        float4 a4 = *(const float4*)(W + (size_t)(m0 + arow) * K + k0 + acol);
        float4 b4 = *(const float4*)(Xb + (size_t)(k0 + brow) * NSEQ + n0 + bcol);
        As[arow][acol + 0] = a4.x; As[arow][acol + 1] = a4.y;
        As[arow][acol + 2] = a4.z; As[arow][acol + 3] = a4.w;
        *(float4*)&Bs[brow][bcol] = b4;
        __syncthreads();
        #pragma unroll
        for (int kk = 0; kk < 16; ++kk) {
            float a[4];
            #pragma unroll
            for (int i = 0; i < 4; ++i) a[i] = As[ty * 4 + i][kk];
            float4 bb = *(const float4*)&Bs[kk][tx * 4];
            #pragma unroll
            for (int i = 0; i < 4; ++i) {
                acc[i][0] += a[i] * bb.x; acc[i][1] += a[i] * bb.y;
                acc[i][2] += a[i] * bb.z; acc[i][3] += a[i] * bb.w;
            }
        }
        __syncthreads();
    }
    #pragma unroll
    for (int i = 0; i < 4; ++i) {
        float bi = BIAS ? bias[m0 + ty * 4 + i] : 0.f;
        float4 r;
        r.x = acc[i][0] + bi; r.y = acc[i][1] + bi;
        r.z = acc[i][2] + bi; r.w = acc[i][3] + bi;
        *(float4*)(Yb + (size_t)(m0 + ty * 4 + i) * NSEQ + n0 + tx * 4) = r;
    }
}

// ---------------- helpers ----------------
static __device__ inline ushort2 pk_bf2(float a, float b) {
    __hip_bfloat162 h = __float22bfloat162_rn(make_float2(a, b));
    return *reinterpret_cast<ushort2*>(&h);
}

template<int CTRL>
static __device__ inline float dpp_f(float x) {
    int r = __builtin_amdgcn_update_dpp(0, __float_as_int(x), CTRL, 0xF, 0xF, true);
    return __int_as_float(r);
}
// reduce over the 16-lane DPP row via rotates (row_ror:1/2/4/8)
static __device__ inline float row_max16(float x) {
    x = fmaxf(x, dpp_f<0x121>(x));
    x = fmaxf(x, dpp_f<0x122>(x));
    x = fmaxf(x, dpp_f<0x124>(x));
    x = fmaxf(x, dpp_f<0x128>(x));
    return x;
}
static __device__ inline float row_sum16(float x) {
    x += dpp_f<0x121>(x);
    x += dpp_f<0x122>(x);
    x += dpp_f<0x124>(x);
    x += dpp_f<0x128>(x);
    return x;
}

// ---------------- MFMA bf16 flash attention ----------------
// grid (16, 8, 4), block 256 (4 waves). Q-tile 128 (32/wave, 2 m-tiles), j-tile 64.
__global__ __launch_bounds__(256)
void attn_mfma(const float* __restrict__ qkv, float* __restrict__ out)
{
    const int tid  = threadIdx.x;
    const int w    = tid >> 6;
    const int lane = tid & 63;
    const int l15  = lane & 15;
    const int quad = lane >> 4;
    const int i0   = blockIdx.x * 128;
    const int h    = blockIdx.y;
    const int b    = blockIdx.z;

    __shared__ __align__(16) char smem[36864];
    ushort* Qs = (ushort*)smem;                          // [128][LDF]
    ushort* Ps = (ushort*)smem + (size_t)w * 32 * LDF;   // per-wave [32][LDF] (overlaps Qs)
    ushort* Ks = (ushort*)(smem + 18432);                // [64][LDF], layout [j][d]
    ushort* Vs = (ushort*)(smem + 18432 + 9216);         // [64][LDF], layout [d][j]
    float*  Os = (float*)smem;                           // [128][65] (epilogue reuse)

    const float* Qg = qkv + ((size_t)b * 1536 + (size_t)h * 64) * NSEQ;
    const float* Kg = Qg + (size_t)512 * NSEQ;
    const float* Vg = Qg + (size_t)1024 * NSEQ;

    // ---- stage Q: global [d][n] -> LDS [i][d], bf16, * SCALE*log? (just SCALE) ----
    {
        const float scale = 0.125f;           // 64^-0.5
        const int ig  = (tid & 31) * 4;       // i offset
        const int dgb = (tid >> 5) * 8;       // d base (0..56)
        #pragma unroll
        for (int half = 0; half < 2; ++half) {
            const int d0 = dgb + half * 4;
            float4 r0 = *(const float4*)(Qg + (size_t)(d0 + 0) * NSEQ + i0 + ig);
            float4 r1 = *(const float4*)(Qg + (size_t)(d0 + 1) * NSEQ + i0 + ig);
            float4 r2 = *(const float4*)(Qg + (size_t)(d0 + 2) * NSEQ + i0 + ig);
            float4 r3 = *(const float4*)(Qg + (size_t)(d0 + 3) * NSEQ + i0 + ig);
            const float* a0 = (const float*)&r0; const float* a1 = (const float*)&r1;
            const float* a2 = (const float*)&r2; const float* a3 = (const float*)&r3;
            #pragma unroll
            for (int c = 0; c < 4; ++c) {
                ushort2 lo = pk_bf2(a0[c] * scale, a1[c] * scale);
                ushort2 hi = pk_bf2(a2[c] * scale, a3[c] * scale);
                *(ushort4*)&Qs[(size_t)(ig + c) * LDF + d0] = make_ushort4(lo.x, lo.y, hi.x, hi.y);
            }
        }
    }
    __syncthreads();

    // Q fragments (A-layout: A[m=l15][k=quad*8+j]) — persistent in registers
    bf16x8 qf[2][2];
    #pragma unroll
    for (int mt = 0; mt < 2; ++mt)
        #pragma unroll
        for (int kk = 0; kk < 2; ++kk)
            qf[mt][kk] = *(const bf16x8*)&Qs[(size_t)(w * 32 + mt * 16 + l15) * LDF + kk * 32 + quad * 8];

    f32x4 Oacc[2][4];
    const f32x4 zero4 = {0.f, 0.f, 0.f, 0.f};
    #pragma unroll
    for (int mt = 0; mt < 2; ++mt)
        #pragma unroll
        for (int dt = 0; dt < 4; ++dt) Oacc[mt][dt] = zero4;
    float mrow[2][4], lrow[2][4];
    #pragma unroll
    for (int mt = 0; mt < 2; ++mt)
        #pragma unroll
        for (int r = 0; r < 4; ++r) { mrow[mt][r] = -1e30f; lrow[mt][r] = 0.f; }

    for (int j0 = 0; j0 < NSEQ; j0 += 64) {
        __syncthreads();   // previous tile fully consumed (also orders Q-frag reads vs P writes)

        // ---- stage K: global K^T[d][j] -> LDS Ks[j][d] (transpose), bf16 ----
        {
            const int jg = (tid & 15) * 4;
            const int dg = (tid >> 4) * 4;
            float4 r0 = *(const float4*)(Kg + (size_t)(dg + 0) * NSEQ + j0 + jg);
            float4 r1 = *(const float4*)(Kg + (size_t)(dg + 1) * NSEQ + j0 + jg);
            float4 r2 = *(const float4*)(Kg + (size_t)(dg + 2) * NSEQ + j0 + jg);
            float4 r3 = *(const float4*)(Kg + (size_t)(dg + 3) * NSEQ + j0 + jg);
            const float* a0 = (const float*)&r0; const float* a1 = (const float*)&r1;
            const float* a2 = (const float*)&r2; const float* a3 = (const float*)&r3;
            #pragma unroll
            for (int c = 0; c < 4; ++c) {
                ushort2 lo = pk_bf2(a0[c], a1[c]);
                ushort2 hi = pk_bf2(a2[c], a3[c]);
                *(ushort4*)&Ks[(size_t)(jg + c) * LDF + dg] = make_ushort4(lo.x, lo.y, hi.x, hi.y);
            }
        }
        // ---- stage V: global V[d][j] -> LDS Vs[d][j], bf16 ----
        {
            const int jg = (tid & 15) * 4;
            const int d0 = tid >> 4;           // 0..15
            #pragma unroll
            for (int r = 0; r < 4; ++r) {
                const int d = d0 + r * 16;
                float4 v = *(const float4*)(Vg + (size_t)d * NSEQ + j0 + jg);
                const float* vv = (const float*)&v;
                ushort2 lo = pk_bf2(vv[0], vv[1]);
                ushort2 hi = pk_bf2(vv[2], vv[3]);
                *(ushort4*)&Vs[(size_t)d * LDF + jg] = make_ushort4(lo.x, lo.y, hi.x, hi.y);
            }
        }
        __syncthreads();

        // ---- QK^T: S[mt] is 16x64 in C-layout (row=quad*4+reg, col=nt*16+l15) ----
        f32x4 S[2][4];
        #pragma unroll
        for (int mt = 0; mt < 2; ++mt)
            #pragma unroll
            for (int nt = 0; nt < 4; ++nt) S[mt][nt] = zero4;
        #pragma unroll
        for (int nt = 0; nt < 4; ++nt) {
            #pragma unroll
            for (int kk = 0; kk < 2; ++kk) {
                bf16x8 kf = *(const bf16x8*)&Ks[(size_t)(nt * 16 + l15) * LDF + kk * 32 + quad * 8];
                S[0][nt] = __builtin_amdgcn_mfma_f32_16x16x32_bf16(qf[0][kk], kf, S[0][nt], 0, 0, 0);
                S[1][nt] = __builtin_amdgcn_mfma_f32_16x16x32_bf16(qf[1][kk], kf, S[1][nt], 0, 0, 0);
            }
        }

        // ---- online softmax (per row; rows live across the 16-lane DPP row) ----
        #pragma unroll
        for (int mt = 0; mt < 2; ++mt) {
            #pragma unroll
            for (int reg = 0; reg < 4; ++reg) {
                float mx = fmaxf(fmaxf(S[mt][0][reg], S[mt][1][reg]),
                                 fmaxf(S[mt][2][reg], S[mt][3][reg]));
                mx = row_max16(mx);
                float mnew = fmaxf(mrow[mt][reg], mx);
                float al   = __expf(mrow[mt][reg] - mnew);
                mrow[mt][reg] = mnew;
                float ps = 0.f;
                #pragma unroll
                for (int nt = 0; nt < 4; ++nt) {
                    float p = __expf(S[mt][nt][reg] - mnew);
                    S[mt][nt][reg] = p;
                    ps += p;
                }
                ps = row_sum16(ps);
                lrow[mt][reg] = lrow[mt][reg] * al + ps;
                #pragma unroll
                for (int dt = 0; dt < 4; ++dt) Oacc[mt][dt][reg] *= al;
            }
            // ---- P (C-layout) -> LDS [i][j] bf16 (per-wave region, same-wave RAW) ----
            #pragma unroll
            for (int nt = 0; nt < 4; ++nt) {
                ushort2 ab = pk_bf2(S[mt][nt][0], S[mt][nt][1]);
                ushort2 cd = pk_bf2(S[mt][nt][2], S[mt][nt][3]);
                const int base = (mt * 16 + quad * 4) * LDF + nt * 16 + l15;
                Ps[base]           = ab.x;
                Ps[base + LDF]     = ab.y;
                Ps[base + 2 * LDF] = cd.x;
                Ps[base + 3 * LDF] = cd.y;
            }
        }

        // ---- PV: A = P[i][j], B = V[j][d] (from Vs[d][j]) ----
        #pragma unroll
        for (int kk = 0; kk < 2; ++kk) {
            bf16x8 pf0 = *(const bf16x8*)&Ps[(size_t)(0 * 16 + l15) * LDF + kk * 32 + quad * 8];
            bf16x8 pf1 = *(const bf16x8*)&Ps[(size_t)(1 * 16 + l15) * LDF + kk * 32 + quad * 8];
            #pragma unroll
            for (int dt = 0; dt < 4; ++dt) {
                bf16x8 vf = *(const bf16x8*)&Vs[(size_t)(dt * 16 + l15) * LDF + kk * 32 + quad * 8];
                Oacc[0][dt] = __builtin_amdgcn_mfma_f32_16x16x32_bf16(pf0, vf, Oacc[0][dt], 0, 0, 0);
                Oacc[1][dt] = __builtin_amdgcn_mfma_f32_16x16x32_bf16(pf1, vf, Oacc[1][dt], 0, 0, 0);
            }
        }
    }

    // ---- epilogue: normalize, transpose through LDS, coalesced store ----
    __syncthreads();   // everyone done with Ks/Vs/Ps before Os overwrites
    float rinv[2][4];
    #pragma unroll
    for (int mt = 0; mt < 2; ++mt)
        #pragma unroll
        for (int r = 0; r < 4; ++r) rinv[mt][r] = 1.f / lrow[mt][r];
    #pragma unroll
    for (int mt = 0; mt < 2; ++mt)
        #pragma unroll
        for (int dt = 0; dt < 4; ++dt)
            #pragma unroll
            for (int reg = 0; reg < 4; ++reg)
                Os[(size_t)(w * 32 + mt * 16 + quad * 4 + reg) * 65 + dt * 16 + l15] =
                    Oacc[mt][dt][reg] * rinv[mt][reg];
    __syncthreads();

    float* Ob = out + ((size_t)b * 512 + (size_t)h * 64) * NSEQ + i0;
    const int il  = tid & 127;
    const int dg2 = tid >> 7;
    #pragma unroll
    for (int r = 0; r < 32; ++r) {
        const int d = dg2 + r * 2;
        Ob[(size_t)d * NSEQ + il] = Os[(size_t)il * 65 + d];
    }
}

extern "C" void kernel_launch(void* const* d_in, const int* in_sizes, int n_in,
                              void* d_out, int out_size, void* d_ws, size_t ws_size,
                              hipStream_t stream)
{
    const float* x     = (const float*)d_in[0];   // (4,256,2048)
    const float* w_qkv = (const float*)d_in[1];   // (1536,256)
    const float* w_out = (const float*)d_in[2];   // (256,512)
    const float* b_out = (const float*)d_in[3];   // (256,)
    float* out  = (float*)d_out;                  // (4,256,2048)

    float* qkv  = (float*)d_ws;                              // 50 MB
    float* attn = qkv + (size_t)BATCH * 1536 * NSEQ;         // 16 MB

    gemm_wx<false><<<dim3(NSEQ / 64, 1536 / 64, BATCH), 256, 0, stream>>>(
        w_qkv, x, nullptr, qkv, 256);
    attn_mfma<<<dim3(NSEQ / 128, 8, BATCH), 256, 0, stream>>>(qkv, attn);
    gemm_wx<true><<<dim3(NSEQ / 64, 256 / 64, BATCH), 256, 0, stream>>>(
        w_out, attn, b_out, out, 512);
}

// Round 3
// 271.498 us; speedup vs baseline: 4.3926x; 1.3151x over previous
//
#include <hip/hip_runtime.h>
#include <hip/hip_bf16.h>

#define NSEQ 2048
#define BATCH 4

typedef __attribute__((ext_vector_type(8))) short bf16x8;
typedef __attribute__((ext_vector_type(4))) float f32x4;

static __device__ inline ushort2 pk_bf2(float a, float b) {
    __hip_bfloat162 h = __float22bfloat162_rn(make_float2(a, b));
    return *reinterpret_cast<ushort2*>(&h);
}
static __device__ inline ushort bf1(float a) { return pk_bf2(a, a).x; }

template<int CTRL>
static __device__ inline float dpp_f(float x) {
    int r = __builtin_amdgcn_update_dpp(0, __float_as_int(x), CTRL, 0xF, 0xF, true);
    return __int_as_float(r);
}
static __device__ inline float row_max16(float x) {
    x = fmaxf(x, dpp_f<0x121>(x));
    x = fmaxf(x, dpp_f<0x122>(x));
    x = fmaxf(x, dpp_f<0x124>(x));
    x = fmaxf(x, dpp_f<0x128>(x));
    return x;
}
static __device__ inline float row_sum16(float x) {
    x += dpp_f<0x121>(x);
    x += dpp_f<0x122>(x);
    x += dpp_f<0x124>(x);
    x += dpp_f<0x128>(x);
    return x;
}

// ---------------- fp32 -> bf16 bulk convert (x, w_qkv, w_out) ----------------
__global__ __launch_bounds__(256)
void cvt_bf16(const float* __restrict__ x, const float* __restrict__ wq,
              const float* __restrict__ wo, ushort* __restrict__ xb,
              ushort* __restrict__ wqb, ushort* __restrict__ wob)
{
    const size_t NX = 2097152 / 4, NQ = 393216 / 4, NO = 131072 / 4;
    size_t i = (size_t)blockIdx.x * blockDim.x + threadIdx.x;
    const float* s; ushort* d; size_t off;
    if (i < NX)            { s = x;  d = xb;  off = i; }
    else if (i < NX + NQ)  { s = wq; d = wqb; off = i - NX; }
    else if (i < NX + NQ + NO) { s = wo; d = wob; off = i - NX - NQ; }
    else return;
    float4 v = ((const float4*)s)[off];
    ushort2 lo = pk_bf2(v.x, v.y), hi = pk_bf2(v.z, v.w);
    ((ushort4*)d)[off] = make_ushort4(lo.x, lo.y, hi.x, hi.y);
}

// ---------------- bf16 MFMA GEMM: Y[b][o][n] = sum_k A[o][k] * X[b][k][n] ----------------
// 128x128 tile, BK=64, 256 threads (4 waves; wave w owns rows w*32..w*32+31).
// OUT_BF16: bf16 output (QSCALE: rows o<512 scaled by 0.125). Else fp32 + bias.
template<bool OUT_BF16, bool QSCALE>
__global__ __launch_bounds__(256)
void gemm_mfma(const ushort* __restrict__ A, const ushort* __restrict__ X,
               const float* __restrict__ bias, void* __restrict__ Yv,
               const int M, const int K)
{
    const int N = NSEQ;
    const int tid = threadIdx.x;
    const int w = tid >> 6, l15 = tid & 15, quad = (tid & 63) >> 4;
    const int n0 = blockIdx.x * 128, o0 = blockIdx.y * 128, b = blockIdx.z;
    const ushort* Xb = X + (size_t)b * K * N;

    __shared__ __align__(16) ushort As[128][72];   // [m][k]
    __shared__ __align__(16) ushort Bs[128][72];   // [n][k]

    f32x4 acc[2][8];
    const f32x4 z4 = {0.f, 0.f, 0.f, 0.f};
    #pragma unroll
    for (int mt = 0; mt < 2; ++mt)
        #pragma unroll
        for (int nt = 0; nt < 8; ++nt) acc[mt][nt] = z4;

    for (int k0 = 0; k0 < K; k0 += 64) {
        __syncthreads();
        // stage A: [m][k] direct copy, 16B chunks
        #pragma unroll
        for (int r = 0; r < 2; ++r)
            #pragma unroll
            for (int c = 0; c < 2; ++c) {
                const int m  = (tid >> 2) + r * 64;
                const int ch = (tid & 3) * 2 + c;
                *(uint4*)&As[m][ch * 8] =
                    *(const uint4*)&A[(size_t)(o0 + m) * K + k0 + ch * 8];
            }
        // stage B: [k][n] global -> [n][k] LDS (4x4 register transpose)
        #pragma unroll
        for (int it = 0; it < 2; ++it) {
            const int kb = (tid & 15) * 4;
            const int nb = (tid >> 4) * 4 + it * 64;
            ushort4 r0 = *(const ushort4*)&Xb[(size_t)(k0 + kb + 0) * N + n0 + nb];
            ushort4 r1 = *(const ushort4*)&Xb[(size_t)(k0 + kb + 1) * N + n0 + nb];
            ushort4 r2 = *(const ushort4*)&Xb[(size_t)(k0 + kb + 2) * N + n0 + nb];
            ushort4 r3 = *(const ushort4*)&Xb[(size_t)(k0 + kb + 3) * N + n0 + nb];
            const ushort* p0 = (const ushort*)&r0;
            const ushort* p1 = (const ushort*)&r1;
            const ushort* p2 = (const ushort*)&r2;
            const ushort* p3 = (const ushort*)&r3;
            #pragma unroll
            for (int c = 0; c < 4; ++c)
                *(ushort4*)&Bs[nb + c][kb] = make_ushort4(p0[c], p1[c], p2[c], p3[c]);
        }
        __syncthreads();
        #pragma unroll
        for (int kk = 0; kk < 2; ++kk) {
            bf16x8 a0 = *(const bf16x8*)&As[w * 32 + l15][kk * 32 + quad * 8];
            bf16x8 a1 = *(const bf16x8*)&As[w * 32 + 16 + l15][kk * 32 + quad * 8];
            #pragma unroll
            for (int nt = 0; nt < 8; ++nt) {
                bf16x8 bb = *(const bf16x8*)&Bs[nt * 16 + l15][kk * 32 + quad * 8];
                acc[0][nt] = __builtin_amdgcn_mfma_f32_16x16x32_bf16(a0, bb, acc[0][nt], 0, 0, 0);
                acc[1][nt] = __builtin_amdgcn_mfma_f32_16x16x32_bf16(a1, bb, acc[1][nt], 0, 0, 0);
            }
        }
    }

    if (OUT_BF16) {
        ushort* Y = (ushort*)Yv + (size_t)b * M * N;
        const float sc = (QSCALE && o0 < 512) ? 0.125f : 1.0f;
        #pragma unroll
        for (int mt = 0; mt < 2; ++mt)
            #pragma unroll
            for (int nt = 0; nt < 8; ++nt)
                #pragma unroll
                for (int reg = 0; reg < 4; ++reg) {
                    const int o = o0 + w * 32 + mt * 16 + quad * 4 + reg;
                    const int n = n0 + nt * 16 + l15;
                    Y[(size_t)o * N + n] = bf1(acc[mt][nt][reg] * sc);
                }
    } else {
        float* Y = (float*)Yv + (size_t)b * M * N;
        #pragma unroll
        for (int mt = 0; mt < 2; ++mt)
            #pragma unroll
            for (int reg = 0; reg < 4; ++reg) {
                const int o = o0 + w * 32 + mt * 16 + quad * 4 + reg;
                const float bi = bias[o];
                #pragma unroll
                for (int nt = 0; nt < 8; ++nt) {
                    const int n = n0 + nt * 16 + l15;
                    Y[(size_t)o * N + n] = acc[mt][nt][reg] + bi;
                }
            }
    }
}

// ---------------- repack Q,K: qkvb [b][o][n] -> Qt/Kt [(b*8+h)*2048+n][64] ----------------
__global__ __launch_bounds__(256)
void repack_qk(const ushort* __restrict__ qkvb, ushort* __restrict__ Qt,
               ushort* __restrict__ Kt)
{
    const int tid = threadIdx.x;
    const int n0  = blockIdx.x * 128;
    const int bh  = blockIdx.y;          // b*8+h
    const int b   = bh >> 3, h = bh & 7;
    const int isK = blockIdx.z;
    const ushort* src = qkvb + ((size_t)b * 1536 + (size_t)isK * 512 + h * 64) * NSEQ;
    ushort* dst = (isK ? Kt : Qt) + ((size_t)bh * NSEQ + n0) * 64;

    __shared__ __align__(16) ushort T[128][72];   // [n][d]

    #pragma unroll
    for (int it = 0; it < 2; ++it) {
        const int d4 = (tid & 15) * 4;
        const int n4 = (tid >> 4) * 4 + it * 64;
        ushort4 r0 = *(const ushort4*)&src[(size_t)(d4 + 0) * NSEQ + n0 + n4];
        ushort4 r1 = *(const ushort4*)&src[(size_t)(d4 + 1) * NSEQ + n0 + n4];
        ushort4 r2 = *(const ushort4*)&src[(size_t)(d4 + 2) * NSEQ + n0 + n4];
        ushort4 r3 = *(const ushort4*)&src[(size_t)(d4 + 3) * NSEQ + n0 + n4];
        const ushort* p0 = (const ushort*)&r0;
        const ushort* p1 = (const ushort*)&r1;
        const ushort* p2 = (const ushort*)&r2;
        const ushort* p3 = (const ushort*)&r3;
        #pragma unroll
        for (int c = 0; c < 4; ++c)
            *(ushort4*)&T[n4 + c][d4] = make_ushort4(p0[c], p1[c], p2[c], p3[c]);
    }
    __syncthreads();
    {
        const int n = tid >> 1;
        const int half = (tid & 1) * 32;
        #pragma unroll
        for (int q = 0; q < 4; ++q)
            *(uint4*)&dst[(size_t)n * 64 + half + q * 8] =
                *(const uint4*)&T[n][half + q * 8];
    }
}

// ---------------- flash attention, all-global operands, LDS only for P ----------------
// grid (16, 8, 4), block 256 (4 waves, NO __syncthreads). 32 queries/wave.
__global__ __launch_bounds__(256)
void attn2(const ushort* __restrict__ Qt, const ushort* __restrict__ Kt,
           const ushort* __restrict__ qkvb, ushort* __restrict__ attnb)
{
    const int tid  = threadIdx.x;
    const int w    = tid >> 6;
    const int lane = tid & 63;
    const int l15  = lane & 15;
    const int quad = lane >> 4;
    const int i0   = blockIdx.x * 128;
    const int h    = blockIdx.y;
    const int b    = blockIdx.z;
    const int bh   = b * 8 + h;

    __shared__ __align__(16) ushort Ps_all[4][32][72];
    ushort* Ps = &Ps_all[w][0][0];

    const ushort* Qrow = Qt + (size_t)bh * NSEQ * 64;
    const ushort* Krow = Kt + (size_t)bh * NSEQ * 64;
    const ushort* Vrow = qkvb + ((size_t)b * 1536 + 1024 + h * 64) * NSEQ;

    // Q fragments (A-layout), pre-scaled by 0.125 at GEMM1
    bf16x8 qf[2][2];
    #pragma unroll
    for (int mt = 0; mt < 2; ++mt)
        #pragma unroll
        for (int kk = 0; kk < 2; ++kk)
            qf[mt][kk] = *(const bf16x8*)
                &Qrow[(size_t)(i0 + w * 32 + mt * 16 + l15) * 64 + kk * 32 + quad * 8];

    f32x4 Oacc[2][4];
    const f32x4 z4 = {0.f, 0.f, 0.f, 0.f};
    #pragma unroll
    for (int mt = 0; mt < 2; ++mt)
        #pragma unroll
        for (int dt = 0; dt < 4; ++dt) Oacc[mt][dt] = z4;
    float mrow[2][4], lrow[2][4];
    #pragma unroll
    for (int mt = 0; mt < 2; ++mt)
        #pragma unroll
        for (int r = 0; r < 4; ++r) { mrow[mt][r] = -1e30f; lrow[mt][r] = 0.f; }

    for (int j0 = 0; j0 < NSEQ; j0 += 64) {
        // QK^T: K fragments direct from global (B-layout)
        f32x4 S[2][4];
        #pragma unroll
        for (int mt = 0; mt < 2; ++mt)
            #pragma unroll
            for (int nt = 0; nt < 4; ++nt) S[mt][nt] = z4;
        #pragma unroll
        for (int nt = 0; nt < 4; ++nt)
            #pragma unroll
            for (int kk = 0; kk < 2; ++kk) {
                bf16x8 kf = *(const bf16x8*)
                    &Krow[(size_t)(j0 + nt * 16 + l15) * 64 + kk * 32 + quad * 8];
                S[0][nt] = __builtin_amdgcn_mfma_f32_16x16x32_bf16(qf[0][kk], kf, S[0][nt], 0, 0, 0);
                S[1][nt] = __builtin_amdgcn_mfma_f32_16x16x32_bf16(qf[1][kk], kf, S[1][nt], 0, 0, 0);
            }

        // online softmax (rows across the 16-lane DPP row)
        #pragma unroll
        for (int mt = 0; mt < 2; ++mt) {
            #pragma unroll
            for (int reg = 0; reg < 4; ++reg) {
                float mx = fmaxf(fmaxf(S[mt][0][reg], S[mt][1][reg]),
                                 fmaxf(S[mt][2][reg], S[mt][3][reg]));
                mx = row_max16(mx);
                float mnew = fmaxf(mrow[mt][reg], mx);
                float al   = __expf(mrow[mt][reg] - mnew);
                mrow[mt][reg] = mnew;
                float ps = 0.f;
                #pragma unroll
                for (int nt = 0; nt < 4; ++nt) {
                    float p = __expf(S[mt][nt][reg] - mnew);
                    S[mt][nt][reg] = p;
                    ps += p;
                }
                ps = row_sum16(ps);
                lrow[mt][reg] = lrow[mt][reg] * al + ps;
                #pragma unroll
                for (int dt = 0; dt < 4; ++dt) Oacc[mt][dt][reg] *= al;
            }
            // P (C-layout) -> per-wave LDS [i][j] bf16
            #pragma unroll
            for (int nt = 0; nt < 4; ++nt) {
                ushort2 ab = pk_bf2(S[mt][nt][0], S[mt][nt][1]);
                ushort2 cd = pk_bf2(S[mt][nt][2], S[mt][nt][3]);
                const int base = (mt * 16 + quad * 4) * 72 + nt * 16 + l15;
                Ps[base]          = ab.x;
                Ps[base + 72]     = ab.y;
                Ps[base + 2 * 72] = cd.x;
                Ps[base + 3 * 72] = cd.y;
            }
        }

        // PV: P from per-wave LDS (A-layout), V direct from global (B-layout)
        #pragma unroll
        for (int kk = 0; kk < 2; ++kk) {
            bf16x8 pf0 = *(const bf16x8*)&Ps[(0 * 16 + l15) * 72 + kk * 32 + quad * 8];
            bf16x8 pf1 = *(const bf16x8*)&Ps[(1 * 16 + l15) * 72 + kk * 32 + quad * 8];
            #pragma unroll
            for (int dt = 0; dt < 4; ++dt) {
                bf16x8 vf = *(const bf16x8*)
                    &Vrow[(size_t)(dt * 16 + l15) * NSEQ + j0 + kk * 32 + quad * 8];
                Oacc[0][dt] = __builtin_amdgcn_mfma_f32_16x16x32_bf16(pf0, vf, Oacc[0][dt], 0, 0, 0);
                Oacc[1][dt] = __builtin_amdgcn_mfma_f32_16x16x32_bf16(pf1, vf, Oacc[1][dt], 0, 0, 0);
            }
        }
    }

    // epilogue: normalize, bf16 through per-wave LDS, coalesced store to [c][n]
    float rinv[2][4];
    #pragma unroll
    for (int mt = 0; mt < 2; ++mt)
        #pragma unroll
        for (int r = 0; r < 4; ++r) rinv[mt][r] = 1.f / lrow[mt][r];
    #pragma unroll
    for (int mt = 0; mt < 2; ++mt)
        #pragma unroll
        for (int dt = 0; dt < 4; ++dt)
            #pragma unroll
            for (int reg = 0; reg < 4; ++reg)
                Ps[(mt * 16 + quad * 4 + reg) * 72 + dt * 16 + l15] =
                    bf1(Oacc[mt][dt][reg] * rinv[mt][reg]);

    ushort* Ob = attnb + ((size_t)b * 512 + (size_t)h * 64) * NSEQ;
    const int il  = lane & 31;
    const int dh2 = lane >> 5;
    #pragma unroll
    for (int dd = 0; dd < 32; ++dd) {
        const int d = dh2 * 32 + dd;
        Ob[(size_t)d * NSEQ + i0 + w * 32 + il] = Ps[il * 72 + d];
    }
}

extern "C" void kernel_launch(void* const* d_in, const int* in_sizes, int n_in,
                              void* d_out, int out_size, void* d_ws, size_t ws_size,
                              hipStream_t stream)
{
    const float* x     = (const float*)d_in[0];   // (4,256,2048)
    const float* w_qkv = (const float*)d_in[1];   // (1536,256)
    const float* w_out = (const float*)d_in[2];   // (256,512)
    const float* b_out = (const float*)d_in[3];   // (256,)
    float* out = (float*)d_out;                   // (4,256,2048) fp32

    ushort* xb    = (ushort*)d_ws;                // 2,097,152
    ushort* wqb   = xb   + 2097152;               //   393,216
    ushort* wob   = wqb  + 393216;                //   131,072
    ushort* qkvb  = wob  + 131072;                // 12,582,912
    ushort* Qt    = qkvb + 12582912;              // 4,194,304
    ushort* Kt    = Qt   + 4194304;               // 4,194,304
    ushort* attnb = Kt   + 4194304;               // 4,194,304   (total ~55.6 MB)

    cvt_bf16<<<2560, 256, 0, stream>>>(x, w_qkv, w_out, xb, wqb, wob);

    gemm_mfma<true, true><<<dim3(16, 12, BATCH), 256, 0, stream>>>(
        wqb, xb, nullptr, qkvb, 1536, 256);

    repack_qk<<<dim3(16, 32, 2), 256, 0, stream>>>(qkvb, Qt, Kt);

    attn2<<<dim3(16, 8, BATCH), 256, 0, stream>>>(Qt, Kt, qkvb, attnb);

    gemm_mfma<false, false><<<dim3(16, 2, BATCH), 256, 0, stream>>>(
        wob, attnb, b_out, out, 256, 512);
}